// Round 12
// baseline (128.890 us; speedup 1.0000x reference)
//
#include <hip/hip_runtime.h>

#define B_   4
#define NQ_  512
#define NK_  512
#define D_   512
#define H_   128

typedef __attribute__((ext_vector_type(8))) short short8;
typedef __attribute__((ext_vector_type(4))) float f32x4;

__device__ __forceinline__ float fexp2(float x) { return __builtin_amdgcn_exp2f(x); }
__device__ __forceinline__ float frcp(float x)  { return __builtin_amdgcn_rcpf(x); }
__device__ __forceinline__ unsigned short f2bf(float f) {
    unsigned int u = __builtin_bit_cast(unsigned int, f);
    u += 0x7FFFu + ((u >> 16) & 1u);          // RNE
    return (unsigned short)(u >> 16);
}

// NOTE (R6): hipLaunchCooperativeKernel silently fails under graph capture.
// NOTE (R9): block-local W@V with zero-padded MFMA A-rows + global B-frags is
//            an unverified-broken construction — do not reuse.
// NOTE (R10): score occupancy (16 waves/CU) beats LDS-traffic halving at
//            8 waves/CU — keep the 512-thr 1-row/wave score.

// ws layout (float offsets)
#define WS_EQK   0          // [4096][128] fp32: exp2(2*proj), Q rows 0..2047, K rows 2048..4095
#define WS_WP    524288     // [64] float4 pair table (wn0, wn1, wn0+wn1, 0)
#define WS_WBF   524544     // ushort region: [4][512][512] bf16 softmax weights
#define WS_VT    1048832    // ushort region: [4][512][512] bf16 V^T (d-major)

// ---------------------------------------------------------------------------
// prep2: grid (384), 256 thr.
//   blocks 0..127: proj, 64 rows x 64 cols, FULL K=512, 4x4 acc/thread
//                  (1.0 FLOP/LDS-byte vs R11's 0.67) ->
//                  Eqk = exp2(C2 * X@W) written directly.
//   blocks 128..383: V transpose -> bf16 V^T (R8-identical).
//   block 0 also emits the wp pair table.
// ---------------------------------------------------------------------------
__global__ __launch_bounds__(256) void prep2_kernel(
    const float* __restrict__ Q, const float* __restrict__ K,
    const float* __restrict__ Wq, const float* __restrict__ Wk,
    const float* __restrict__ V, const float* __restrict__ wv,
    float* __restrict__ Eqk, float* __restrict__ wp,
    unsigned short* __restrict__ Vt)
{
    __shared__ __align__(16) float smem[2 * 64 * 68];   // 34.8 KB
    const int t = threadIdx.x;
    const float C2 = 2.88539008177792681472f;   // 2*log2(e)

    if (blockIdx.x == 0 && t < 64) {
        const float2 w2 = reinterpret_cast<const float2*>(wv)[t];
        const float wn0 = -2.0f * w2.x;
        const float wn1 = -2.0f * w2.y;
        reinterpret_cast<float4*>(wp)[t] =
            make_float4(wn0, wn1, wn0 + wn1, 0.0f);
    }

    if (blockIdx.x < 128) {
        // ----- proj: 64 rows x 64 cols, full K, 4x4 acc -----
        const int rt = blockIdx.x >> 1;       // 0..63
        const int ct = blockIdx.x & 1;        // 0..1
        const int r0 = rt * 64;               // combined row (0..4032)
        const bool isQ = r0 < 2048;           // 64-row tile never spans Q/K
        const float* __restrict__ X = isQ ? Q : K;
        const float* __restrict__ W = isQ ? Wq : Wk;
        const int xr0 = isQ ? r0 : r0 - 2048;
        const int c0  = ct * 64;

        float (*At)[68] = (float(*)[68])smem;             // [k][row]
        float (*Wl)[68] = (float(*)[68])(smem + 64 * 68); // [k][col]

        const int cg = t & 15;    // cols 4*cg..+3
        const int rg = t >> 4;    // rows 4*rg..+3
        float acc[4][4] = {};

        for (int kc = 0; kc < 8; ++kc) {
            const int k0 = kc * 64;
            if (kc) __syncthreads();
            // stage X tile (64 rows x 64 k), transposed -> At[k][row]
            #pragma unroll
            for (int p = 0; p < 4; ++p) {
                const int idx = p * 256 + t;       // 0..1023
                const int row = idx >> 4;          // 0..63
                const int kq  = (idx & 15) * 4;
                const float4 v = *reinterpret_cast<const float4*>(
                    X + (size_t)(xr0 + row) * D_ + k0 + kq);
                At[kq + 0][row] = v.x; At[kq + 1][row] = v.y;
                At[kq + 2][row] = v.z; At[kq + 3][row] = v.w;
            }
            // stage W tile (64 k x 64 cols), natural
            #pragma unroll
            for (int p = 0; p < 4; ++p) {
                const int idx = p * 256 + t;       // 0..1023
                const int kr  = idx >> 4;          // 0..63
                const int c4  = (idx & 15) * 4;
                *reinterpret_cast<float4*>(&Wl[kr][c4]) =
                    *reinterpret_cast<const float4*>(
                        W + (size_t)(k0 + kr) * H_ + c0 + c4);
            }
            __syncthreads();

            #pragma unroll 8
            for (int k = 0; k < 64; ++k) {
                const float4 a4 = *reinterpret_cast<const float4*>(&At[k][rg * 4]);
                const float4 b4 = *reinterpret_cast<const float4*>(&Wl[k][cg * 4]);
                const float aa[4] = {a4.x, a4.y, a4.z, a4.w};
                const float bb[4] = {b4.x, b4.y, b4.z, b4.w};
                #pragma unroll
                for (int r = 0; r < 4; ++r)
                    #pragma unroll
                    for (int c = 0; c < 4; ++c)
                        acc[r][c] = fmaf(aa[r], bb[c], acc[r][c]);
            }
        }

        #pragma unroll
        for (int r = 0; r < 4; ++r) {
            float4 o;
            o.x = fexp2(C2 * acc[r][0]); o.y = fexp2(C2 * acc[r][1]);
            o.z = fexp2(C2 * acc[r][2]); o.w = fexp2(C2 * acc[r][3]);
            *reinterpret_cast<float4*>(
                Eqk + (size_t)(r0 + rg * 4 + r) * H_ + c0 + cg * 4) = o;
        }
    } else {
        // ----- transposeV: V (k-major fp32) -> Vt (d-major bf16) -----
        const int id = blockIdx.x - 128;          // 0..255
        const int kt = id & 7, dt = (id >> 3) & 7, b = id >> 6;
        float (*Vl)[69] = (float(*)[69])smem;     // [64][69] = 17.7 KB

        #pragma unroll
        for (int p = 0; p < 4; ++p) {
            const int idx = p * 256 + t;
            const int r  = idx >> 4;
            const int c4 = (idx & 15) * 4;
            const float4 v = *reinterpret_cast<const float4*>(
                V + ((size_t)b * NK_ + kt * 64 + r) * D_ + dt * 64 + c4);
            Vl[r][c4 + 0] = v.x; Vl[r][c4 + 1] = v.y;
            Vl[r][c4 + 2] = v.z; Vl[r][c4 + 3] = v.w;
        }
        __syncthreads();

        #pragma unroll
        for (int p = 0; p < 4; ++p) {
            const int idx = p * 256 + t;
            const int d  = idx >> 4;
            const int k4 = (idx & 15) * 4;
            ushort4 o;
            o.x = f2bf(Vl[k4 + 0][d]); o.y = f2bf(Vl[k4 + 1][d]);
            o.z = f2bf(Vl[k4 + 2][d]); o.w = f2bf(Vl[k4 + 3][d]);
            *reinterpret_cast<ushort4*>(
                Vt + ((size_t)b * D_ + dt * 64 + d) * NK_ + kt * 64 + k4) = o;
        }
    }
}

// ---------------------------------------------------------------------------
// score_softmax fused (R8 verbatim — verified): block = 4 q-rows x all 512 k,
// 512 thr (8 waves). Wave w -> row rb*4 + (w>>1), k-half (w&1)*256.
// score'[q,k] = sum_h wn_h / (1 + Eq_h*Ek_h), 4-way rcp fusion, zero exp2
// in the hot loop. Cross-wave combine via LDS; writes bf16 weights.
// ---------------------------------------------------------------------------
__global__ __launch_bounds__(512, 4) void score_softmax_kernel(
    const float* __restrict__ Eqk, const float* __restrict__ wp,
    const int* __restrict__ valid_lens, unsigned short* __restrict__ Wbf)
{
    const int rb   = blockIdx.x;            // 0..511
    const int t    = threadIdx.x;
    const int w    = __builtin_amdgcn_readfirstlane(t >> 6);   // 0..7
    const int lane = t & 63;
    const int rloc = w >> 1;                // 0..3
    const int half = w & 1;                 // k-half
    const int row  = rb * 4 + rloc;         // 0..2047
    const int b    = row >> 9;

    __shared__ __align__(16) float4 Ks[2 * 64 * 33];   // two 64-k chunks
    __shared__ float redM[4][2], redS[4][2];

    const float4* __restrict__ Q4 =
        reinterpret_cast<const float4*>(Eqk + (size_t)row * H_);
    const float4* __restrict__ wp4 = reinterpret_cast<const float4*>(wp);
    const float4* __restrict__ Kp4 =
        reinterpret_cast<const float4*>(Eqk + (size_t)(2048 + b * NK_) * H_);

    float vals[4];

    for (int c = 0; c < 4; ++c) {
        if (c) __syncthreads();
        #pragma unroll
        for (int p = 0; p < 8; ++p) {
            const int idx = p * 512 + t;        // 0..4095
            const int hh  = idx >> 11;          // 0..1
            const int r   = (idx >> 5) & 63;    // 0..63
            const int h4  = idx & 31;
            Ks[(hh * 64 + r) * 33 + h4] =
                Kp4[(size_t)(hh * 256 + c * 64 + r) * 32 + h4];
        }
        __syncthreads();

        float s = 0.0f;
        #pragma unroll 4
        for (int g = 0; g < 32; ++g) {
            const float4 kv = Ks[(half * 64 + lane) * 33 + g];
            const float4 qa = Q4[g];
            const float4 wa = wp4[2 * g];
            const float4 wb = wp4[2 * g + 1];
            const float e0 = qa.x * kv.x;
            const float e1 = qa.y * kv.y;
            const float e2 = qa.z * kv.z;
            const float e3 = qa.w * kv.w;
            const float D01 = 1.0f + fmaf(e0, e1, e0 + e1);
            const float D23 = 1.0f + fmaf(e2, e3, e2 + e3);
            const float n01 = fmaf(wa.y, e0, fmaf(wa.x, e1, wa.z));
            const float n23 = fmaf(wb.y, e2, fmaf(wb.x, e3, wb.z));
            const float N   = fmaf(n23, D01, n01 * D23);
            s = fmaf(N, frcp(D01 * D23), s);
        }
        vals[c] = s;
    }

    // per-wave masked stats over this wave's 256 k
    const int vl = valid_lens[b];
    const float L2E = 1.44269504088896340736f;
    float m = -1e30f;
    #pragma unroll
    for (int c = 0; c < 4; ++c) {
        const int k = half * 256 + c * 64 + lane;
        vals[c] = (k < vl) ? vals[c] : -1e30f;
        m = fmaxf(m, vals[c]);
    }
    #pragma unroll
    for (int off = 32; off >= 1; off >>= 1)
        m = fmaxf(m, __shfl_xor(m, off, 64));
    float sum = 0.0f;
    #pragma unroll
    for (int c = 0; c < 4; ++c)
        sum += fexp2((vals[c] - m) * L2E);
    #pragma unroll
    for (int off = 32; off >= 1; off >>= 1)
        sum += __shfl_xor(sum, off, 64);

    if (lane == 0) { redM[rloc][half] = m; redS[rloc][half] = sum; }
    __syncthreads();

    const float m0 = redM[rloc][0], m1 = redM[rloc][1];
    const float s0 = redS[rloc][0], s1 = redS[rloc][1];
    const float M  = fmaxf(m0, m1);   // finite: vl>=1 so half 0 has a valid k
    const float S  = fmaf(s0, fexp2((m0 - M) * L2E),
                          s1 * fexp2((m1 - M) * L2E));
    const float inv = frcp(S);

    unsigned short* __restrict__ dst = Wbf + (size_t)row * NK_ + half * 256;
    #pragma unroll
    for (int c = 0; c < 4; ++c)
        dst[c * 64 + lane] = f2bf(fexp2((vals[c] - M) * L2E) * inv);
}

// ---------------------------------------------------------------------------
// av_gemm (bf16 MFMA 16x16x32, R8 verbatim — verified): O[b] = W@V.
// Block 64q x 64d, 4 waves, grid (8,8,4).
// ---------------------------------------------------------------------------
__global__ __launch_bounds__(256) void av_gemm_kernel(
    const unsigned short* __restrict__ Wbf, const unsigned short* __restrict__ Vt,
    float* __restrict__ O)
{
    const int c0 = blockIdx.x * 64;
    const int r0 = blockIdx.y * 64;
    const int b  = blockIdx.z;
    const int t  = threadIdx.x;
    const int wave = __builtin_amdgcn_readfirstlane(t >> 6);
    const int lane = t & 63;
    const int m    = lane & 15;
    const int quad = lane >> 4;

    __shared__ unsigned short Al [64][136];
    __shared__ unsigned short Btl[64][136];

    f32x4 acc0 = {0.f,0.f,0.f,0.f}, acc1 = {0.f,0.f,0.f,0.f};
    f32x4 acc2 = {0.f,0.f,0.f,0.f}, acc3 = {0.f,0.f,0.f,0.f};

    for (int kc = 0; kc < 4; ++kc) {
        if (kc) __syncthreads();
        #pragma unroll
        for (int p = 0; p < 4; ++p) {
            const int idx = p * 256 + t;
            const int rl = idx >> 4;
            const int k8 = (idx & 15) * 8;
            *reinterpret_cast<uint4*>(&Al[rl][k8]) =
                *reinterpret_cast<const uint4*>(
                    Wbf + ((size_t)b * NQ_ + r0 + rl) * NK_ + kc * 128 + k8);
            *reinterpret_cast<uint4*>(&Btl[rl][k8]) =
                *reinterpret_cast<const uint4*>(
                    Vt + ((size_t)b * D_ + c0 + rl) * NK_ + kc * 128 + k8);
        }
        __syncthreads();

        #pragma unroll
        for (int sub = 0; sub < 4; ++sub) {
            const int kcol = sub * 32 + quad * 8;
            const short8 a = *reinterpret_cast<const short8*>(&Al[wave * 16 + m][kcol]);
            const short8 b0 = *reinterpret_cast<const short8*>(&Btl[ 0 + m][kcol]);
            const short8 b1 = *reinterpret_cast<const short8*>(&Btl[16 + m][kcol]);
            const short8 b2 = *reinterpret_cast<const short8*>(&Btl[32 + m][kcol]);
            const short8 b3 = *reinterpret_cast<const short8*>(&Btl[48 + m][kcol]);
            acc0 = __builtin_amdgcn_mfma_f32_16x16x32_bf16(a, b0, acc0, 0, 0, 0);
            acc1 = __builtin_amdgcn_mfma_f32_16x16x32_bf16(a, b1, acc1, 0, 0, 0);
            acc2 = __builtin_amdgcn_mfma_f32_16x16x32_bf16(a, b2, acc2, 0, 0, 0);
            acc3 = __builtin_amdgcn_mfma_f32_16x16x32_bf16(a, b3, acc3, 0, 0, 0);
        }
    }

    const size_t rowbase = (size_t)b * NQ_ + r0 + wave * 16 + quad * 4;
    #pragma unroll
    for (int i = 0; i < 4; ++i) {
        float* __restrict__ orow = O + (rowbase + i) * D_ + c0 + m;
        orow[ 0] = acc0[i];
        orow[16] = acc1[i];
        orow[32] = acc2[i];
        orow[48] = acc3[i];
    }
}

extern "C" void kernel_launch(void* const* d_in, const int* in_sizes, int n_in,
                              void* d_out, int out_size, void* d_ws, size_t ws_size,
                              hipStream_t stream) {
    (void)in_sizes; (void)n_in; (void)out_size; (void)ws_size;

    const float* Q   = (const float*)d_in[0];
    const float* K   = (const float*)d_in[1];
    const float* V   = (const float*)d_in[2];
    const float* Wq  = (const float*)d_in[3];
    const float* Wk  = (const float*)d_in[4];
    const float* wv  = (const float*)d_in[5];
    const int*   vl  = (const int*)d_in[6];
    float* out = (float*)d_out;

    float* ws  = (float*)d_ws;
    float* Eqk = ws + WS_EQK;
    float* wp  = ws + WS_WP;
    unsigned short* Wbf = (unsigned short*)(ws + WS_WBF);
    unsigned short* Vt  = (unsigned short*)(ws + WS_VT);

    prep2_kernel<<<dim3(384), 256, 0, stream>>>(Q, K, Wq, Wk, V, wv, Eqk, wp, Vt);
    score_softmax_kernel<<<dim3(512), 512, 0, stream>>>(Eqk, wp, vl, Wbf);
    av_gemm_kernel<<<dim3(8, 8, 4), 256, 0, stream>>>(Wbf, Vt, out);
}

// Round 13
// 120.731 us; speedup vs baseline: 1.0676x; 1.0676x over previous
//
#include <hip/hip_runtime.h>

#define B_   4
#define NQ_  512
#define NK_  512
#define D_   512
#define H_   128

typedef __attribute__((ext_vector_type(8))) short short8;
typedef __attribute__((ext_vector_type(4))) float f32x4;

__device__ __forceinline__ float fexp2(float x) { return __builtin_amdgcn_exp2f(x); }
__device__ __forceinline__ float frcp(float x)  { return __builtin_amdgcn_rcpf(x); }
__device__ __forceinline__ unsigned short f2bf(float f) {
    unsigned int u = __builtin_bit_cast(unsigned int, f);
    u += 0x7FFFu + ((u >> 16) & 1u);          // RNE
    return (unsigned short)(u >> 16);
}

// NOTE (R6): hipLaunchCooperativeKernel silently fails under graph capture.
// NOTE (R9): block-local W@V with zero-padded MFMA A-rows + global B-frags is
//            an unverified-broken construction — do not reuse.
// NOTE (R10): score occupancy (16 waves/CU) beats LDS-traffic halving at
//            8 waves/CU — keep the 512-thr 1-row/wave score.
// NOTE (R12): 64x64 proj tiles (128 blocks) regressed vs 32x64 (256 blocks):
//            block count/balance > per-thread LDS intensity at this scale.

// ws layout (float offsets)
#define WS_EQK   0          // [4096][128] fp32: exp2(2*proj), Q rows 0..2047, K rows 2048..4095
#define WS_WP    524288     // [64] float4 pair table (wn0, wn1, wn0+wn1, 0)
#define WS_WBF   524544     // ushort region: [4][512][512] bf16 softmax weights
#define WS_VT    1048832    // ushort region: [4][512][512] bf16 V^T (d-major)

// ---------------------------------------------------------------------------
// prep2 (R11 verbatim — verified best): grid (512), 256 thr.
//   blocks 0..255: proj, 32 rows x 64 cols, FULL K=512 ->
//                  Eqk = exp2(C2 * X@W) written directly.
//   blocks 256..511: V transpose -> bf16 V^T.
//   block 0 also emits the wp pair table.
// ---------------------------------------------------------------------------
__global__ __launch_bounds__(256) void prep2_kernel(
    const float* __restrict__ Q, const float* __restrict__ K,
    const float* __restrict__ Wq, const float* __restrict__ Wk,
    const float* __restrict__ V, const float* __restrict__ wv,
    float* __restrict__ Eqk, float* __restrict__ wp,
    unsigned short* __restrict__ Vt)
{
    __shared__ __align__(16) float smem[64 * 36 + 64 * 68];   // 26.6 KB
    const int t = threadIdx.x;
    const float C2 = 2.88539008177792681472f;   // 2*log2(e)

    if (blockIdx.x == 0 && t < 64) {
        const float2 w2 = reinterpret_cast<const float2*>(wv)[t];
        const float wn0 = -2.0f * w2.x;
        const float wn1 = -2.0f * w2.y;
        reinterpret_cast<float4*>(wp)[t] =
            make_float4(wn0, wn1, wn0 + wn1, 0.0f);
    }

    if (blockIdx.x < 256) {
        // ----- proj: 32 rows x 64 cols, full K -----
        const int rt = blockIdx.x >> 1;       // 0..127
        const int ct = blockIdx.x & 1;        // 0..1
        const int r0 = rt * 32;               // combined row (0..4064)
        const bool isQ = r0 < 2048;           // 32-row tile never spans Q/K
        const float* __restrict__ X = isQ ? Q : K;
        const float* __restrict__ W = isQ ? Wq : Wk;
        const int xr0 = isQ ? r0 : r0 - 2048;
        const int c0  = ct * 64;

        float (*At)[36] = (float(*)[36])smem;             // [k][row]
        float (*Wl)[68] = (float(*)[68])(smem + 64 * 36); // [k][col]

        const int cg = t & 15;    // cols 4*cg..+3
        const int rg = t >> 4;    // rows 2*rg..+1
        float acc[2][4] = {};

        for (int kc = 0; kc < 8; ++kc) {
            const int k0 = kc * 64;
            if (kc) __syncthreads();
            // stage X tile (32 rows x 64 k), transposed
            #pragma unroll
            for (int p = 0; p < 2; ++p) {
                const int idx = p * 256 + t;       // 0..511
                const int row = idx >> 4;          // 0..31
                const int kq  = (idx & 15) * 4;
                const float4 v = *reinterpret_cast<const float4*>(
                    X + (size_t)(xr0 + row) * D_ + k0 + kq);
                At[kq + 0][row] = v.x; At[kq + 1][row] = v.y;
                At[kq + 2][row] = v.z; At[kq + 3][row] = v.w;
            }
            // stage W tile (64 k x 64 cols), natural
            #pragma unroll
            for (int p = 0; p < 4; ++p) {
                const int idx = p * 256 + t;       // 0..1023
                const int kr  = idx >> 4;          // 0..63
                const int c4  = (idx & 15) * 4;
                *reinterpret_cast<float4*>(&Wl[kr][c4]) =
                    *reinterpret_cast<const float4*>(
                        W + (size_t)(k0 + kr) * H_ + c0 + c4);
            }
            __syncthreads();

            #pragma unroll 8
            for (int k = 0; k < 64; ++k) {
                const float a0 = At[k][rg * 2];
                const float a1 = At[k][rg * 2 + 1];
                const float4 b4 = *reinterpret_cast<const float4*>(&Wl[k][cg * 4]);
                const float bb[4] = {b4.x, b4.y, b4.z, b4.w};
                #pragma unroll
                for (int c = 0; c < 4; ++c) {
                    acc[0][c] = fmaf(a0, bb[c], acc[0][c]);
                    acc[1][c] = fmaf(a1, bb[c], acc[1][c]);
                }
            }
        }

        #pragma unroll
        for (int r = 0; r < 2; ++r) {
            float4 o;
            o.x = fexp2(C2 * acc[r][0]); o.y = fexp2(C2 * acc[r][1]);
            o.z = fexp2(C2 * acc[r][2]); o.w = fexp2(C2 * acc[r][3]);
            *reinterpret_cast<float4*>(
                Eqk + (size_t)(r0 + rg * 2 + r) * H_ + c0 + cg * 4) = o;
        }
    } else {
        // ----- transposeV: V (k-major fp32) -> Vt (d-major bf16) -----
        const int id = blockIdx.x - 256;          // 0..255
        const int kt = id & 7, dt = (id >> 3) & 7, b = id >> 6;
        float (*Vl)[69] = (float(*)[69])smem;     // [64][69] = 17.7 KB

        #pragma unroll
        for (int p = 0; p < 4; ++p) {
            const int idx = p * 256 + t;
            const int r  = idx >> 4;
            const int c4 = (idx & 15) * 4;
            const float4 v = *reinterpret_cast<const float4*>(
                V + ((size_t)b * NK_ + kt * 64 + r) * D_ + dt * 64 + c4);
            Vl[r][c4 + 0] = v.x; Vl[r][c4 + 1] = v.y;
            Vl[r][c4 + 2] = v.z; Vl[r][c4 + 3] = v.w;
        }
        __syncthreads();

        #pragma unroll
        for (int p = 0; p < 4; ++p) {
            const int idx = p * 256 + t;
            const int d  = idx >> 4;
            const int k4 = (idx & 15) * 4;
            ushort4 o;
            o.x = f2bf(Vl[k4 + 0][d]); o.y = f2bf(Vl[k4 + 1][d]);
            o.z = f2bf(Vl[k4 + 2][d]); o.w = f2bf(Vl[k4 + 3][d]);
            *reinterpret_cast<ushort4*>(
                Vt + ((size_t)b * D_ + dt * 64 + d) * NK_ + kt * 64 + k4) = o;
        }
    }
}

// ---------------------------------------------------------------------------
// score_softmax fused: block = 4 q-rows x all 512 k, 512 thr (8 waves).
// Wave w -> row rb*4 + (w>>1), k-half (w&1)*256.
// score'[q,k] = sum_h wn_h / (1 + Eq_h*Ek_h), 4-way rcp fusion, zero exp2
// in the hot loop. Cross-wave combine via LDS; writes bf16 weights.
// R13 micro-opt: epilogue reuses e[c] from the sum pass and rescales by the
// wave-uniform exp2((m-M))·inv factor (exact; saves 4 exp2/lane).
// ---------------------------------------------------------------------------
__global__ __launch_bounds__(512, 4) void score_softmax_kernel(
    const float* __restrict__ Eqk, const float* __restrict__ wp,
    const int* __restrict__ valid_lens, unsigned short* __restrict__ Wbf)
{
    const int rb   = blockIdx.x;            // 0..511
    const int t    = threadIdx.x;
    const int w    = __builtin_amdgcn_readfirstlane(t >> 6);   // 0..7
    const int lane = t & 63;
    const int rloc = w >> 1;                // 0..3
    const int half = w & 1;                 // k-half
    const int row  = rb * 4 + rloc;         // 0..2047
    const int b    = row >> 9;

    __shared__ __align__(16) float4 Ks[2 * 64 * 33];   // two 64-k chunks
    __shared__ float redM[4][2], redS[4][2];

    const float4* __restrict__ Q4 =
        reinterpret_cast<const float4*>(Eqk + (size_t)row * H_);
    const float4* __restrict__ wp4 = reinterpret_cast<const float4*>(wp);
    const float4* __restrict__ Kp4 =
        reinterpret_cast<const float4*>(Eqk + (size_t)(2048 + b * NK_) * H_);

    float vals[4];

    for (int c = 0; c < 4; ++c) {
        if (c) __syncthreads();
        #pragma unroll
        for (int p = 0; p < 8; ++p) {
            const int idx = p * 512 + t;        // 0..4095
            const int hh  = idx >> 11;          // 0..1
            const int r   = (idx >> 5) & 63;    // 0..63
            const int h4  = idx & 31;
            Ks[(hh * 64 + r) * 33 + h4] =
                Kp4[(size_t)(hh * 256 + c * 64 + r) * 32 + h4];
        }
        __syncthreads();

        float s = 0.0f;
        #pragma unroll 4
        for (int g = 0; g < 32; ++g) {
            const float4 kv = Ks[(half * 64 + lane) * 33 + g];
            const float4 qa = Q4[g];
            const float4 wa = wp4[2 * g];
            const float4 wb = wp4[2 * g + 1];
            const float e0 = qa.x * kv.x;
            const float e1 = qa.y * kv.y;
            const float e2 = qa.z * kv.z;
            const float e3 = qa.w * kv.w;
            const float D01 = 1.0f + fmaf(e0, e1, e0 + e1);
            const float D23 = 1.0f + fmaf(e2, e3, e2 + e3);
            const float n01 = fmaf(wa.y, e0, fmaf(wa.x, e1, wa.z));
            const float n23 = fmaf(wb.y, e2, fmaf(wb.x, e3, wb.z));
            const float N   = fmaf(n23, D01, n01 * D23);
            s = fmaf(N, frcp(D01 * D23), s);
        }
        vals[c] = s;
    }

    // per-wave masked stats over this wave's 256 k
    const int vl = valid_lens[b];
    const float L2E = 1.44269504088896340736f;
    float m = -1e30f;
    #pragma unroll
    for (int c = 0; c < 4; ++c) {
        const int k = half * 256 + c * 64 + lane;
        vals[c] = (k < vl) ? vals[c] : -1e30f;
        m = fmaxf(m, vals[c]);
    }
    #pragma unroll
    for (int off = 32; off >= 1; off >>= 1)
        m = fmaxf(m, __shfl_xor(m, off, 64));
    float e[4];
    float sum = 0.0f;
    #pragma unroll
    for (int c = 0; c < 4; ++c) {
        e[c] = fexp2((vals[c] - m) * L2E);     // masked -> exactly 0
        sum += e[c];
    }
    #pragma unroll
    for (int off = 32; off >= 1; off >>= 1)
        sum += __shfl_xor(sum, off, 64);

    if (lane == 0) { redM[rloc][half] = m; redS[rloc][half] = sum; }
    __syncthreads();

    const float m0 = redM[rloc][0], m1 = redM[rloc][1];
    const float s0 = redS[rloc][0], s1 = redS[rloc][1];
    const float M  = fmaxf(m0, m1);   // finite: vl>=1 so half 0 has a valid k
    const float S  = fmaf(s0, fexp2((m0 - M) * L2E),
                          s1 * fexp2((m1 - M) * L2E));
    // exp2((vals[c]-M)) / S == e[c] * exp2((m-M)) / S  (m wave-uniform)
    const float scale = fexp2((m - M) * L2E) * frcp(S);

    unsigned short* __restrict__ dst = Wbf + (size_t)row * NK_ + half * 256;
    #pragma unroll
    for (int c = 0; c < 4; ++c)
        dst[c * 64 + lane] = f2bf(e[c] * scale);
}

// ---------------------------------------------------------------------------
// av_gemm (bf16 MFMA 16x16x32, R8 verbatim — verified): O[b] = W@V.
// Block 64q x 64d, 4 waves, grid (8,8,4).
// ---------------------------------------------------------------------------
__global__ __launch_bounds__(256) void av_gemm_kernel(
    const unsigned short* __restrict__ Wbf, const unsigned short* __restrict__ Vt,
    float* __restrict__ O)
{
    const int c0 = blockIdx.x * 64;
    const int r0 = blockIdx.y * 64;
    const int b  = blockIdx.z;
    const int t  = threadIdx.x;
    const int wave = __builtin_amdgcn_readfirstlane(t >> 6);
    const int lane = t & 63;
    const int m    = lane & 15;
    const int quad = lane >> 4;

    __shared__ unsigned short Al [64][136];
    __shared__ unsigned short Btl[64][136];

    f32x4 acc0 = {0.f,0.f,0.f,0.f}, acc1 = {0.f,0.f,0.f,0.f};
    f32x4 acc2 = {0.f,0.f,0.f,0.f}, acc3 = {0.f,0.f,0.f,0.f};

    for (int kc = 0; kc < 4; ++kc) {
        if (kc) __syncthreads();
        #pragma unroll
        for (int p = 0; p < 4; ++p) {
            const int idx = p * 256 + t;
            const int rl = idx >> 4;
            const int k8 = (idx & 15) * 8;
            *reinterpret_cast<uint4*>(&Al[rl][k8]) =
                *reinterpret_cast<const uint4*>(
                    Wbf + ((size_t)b * NQ_ + r0 + rl) * NK_ + kc * 128 + k8);
            *reinterpret_cast<uint4*>(&Btl[rl][k8]) =
                *reinterpret_cast<const uint4*>(
                    Vt + ((size_t)b * D_ + c0 + rl) * NK_ + kc * 128 + k8);
        }
        __syncthreads();

        #pragma unroll
        for (int sub = 0; sub < 4; ++sub) {
            const int kcol = sub * 32 + quad * 8;
            const short8 a = *reinterpret_cast<const short8*>(&Al[wave * 16 + m][kcol]);
            const short8 b0 = *reinterpret_cast<const short8*>(&Btl[ 0 + m][kcol]);
            const short8 b1 = *reinterpret_cast<const short8*>(&Btl[16 + m][kcol]);
            const short8 b2 = *reinterpret_cast<const short8*>(&Btl[32 + m][kcol]);
            const short8 b3 = *reinterpret_cast<const short8*>(&Btl[48 + m][kcol]);
            acc0 = __builtin_amdgcn_mfma_f32_16x16x32_bf16(a, b0, acc0, 0, 0, 0);
            acc1 = __builtin_amdgcn_mfma_f32_16x16x32_bf16(a, b1, acc1, 0, 0, 0);
            acc2 = __builtin_amdgcn_mfma_f32_16x16x32_bf16(a, b2, acc2, 0, 0, 0);
            acc3 = __builtin_amdgcn_mfma_f32_16x16x32_bf16(a, b3, acc3, 0, 0, 0);
        }
    }

    const size_t rowbase = (size_t)b * NQ_ + r0 + wave * 16 + quad * 4;
    #pragma unroll
    for (int i = 0; i < 4; ++i) {
        float* __restrict__ orow = O + (rowbase + i) * D_ + c0 + m;
        orow[ 0] = acc0[i];
        orow[16] = acc1[i];
        orow[32] = acc2[i];
        orow[48] = acc3[i];
    }
}

extern "C" void kernel_launch(void* const* d_in, const int* in_sizes, int n_in,
                              void* d_out, int out_size, void* d_ws, size_t ws_size,
                              hipStream_t stream) {
    (void)in_sizes; (void)n_in; (void)out_size; (void)ws_size;

    const float* Q   = (const float*)d_in[0];
    const float* K   = (const float*)d_in[1];
    const float* V   = (const float*)d_in[2];
    const float* Wq  = (const float*)d_in[3];
    const float* Wk  = (const float*)d_in[4];
    const float* wv  = (const float*)d_in[5];
    const int*   vl  = (const int*)d_in[6];
    float* out = (float*)d_out;

    float* ws  = (float*)d_ws;
    float* Eqk = ws + WS_EQK;
    float* wp  = ws + WS_WP;
    unsigned short* Wbf = (unsigned short*)(ws + WS_WBF);
    unsigned short* Vt  = (unsigned short*)(ws + WS_VT);

    prep2_kernel<<<dim3(512), 256, 0, stream>>>(Q, K, Wq, Wk, V, wv, Eqk, wp, Vt);
    score_softmax_kernel<<<dim3(512), 512, 0, stream>>>(Eqk, wp, vl, Wbf);
    av_gemm_kernel<<<dim3(8, 8, 4), 256, 0, stream>>>(Wbf, Vt, out);
}